// Round 5
// baseline (135.316 us; speedup 1.0000x reference)
//
#include <hip/hip_runtime.h>

typedef float v2f __attribute__((ext_vector_type(2)));

#define W_IMG   128
#define H_IMG   128
#define HW_IMG  16384
#define FX_C    128.0f
#define FY_C    128.0f
#define CX_C    64.0f
#define CY_C    64.0f
#define LOG2E_F 1.4426950408889634f
#define CHUNK   64

// ---------------------------------------------------------------------------
// Inline per-gaussian projection: {px, py, a2, op}, a2 = -0.5/var*log2(e).
// ---------------------------------------------------------------------------
__device__ __forceinline__ float4 proj_of(
    const float* __restrict__ pos, const float* __restrict__ opac,
    const float* __restrict__ scl, const float* __restrict__ qv,
    const float* __restrict__ tv, int i)
{
    float qw = qv[0], qx = qv[1], qy = qv[2], qz = qv[3];
    float qn = sqrtf(qw*qw + qx*qx + qy*qy + qz*qz);
    qw /= qn; qx /= qn; qy /= qn; qz /= qn;

    float R00 = 1.f - 2.f*(qy*qy + qz*qz), R01 = 2.f*(qx*qy - qz*qw), R02 = 2.f*(qx*qz + qy*qw);
    float R10 = 2.f*(qx*qy + qz*qw), R11 = 1.f - 2.f*(qx*qx + qz*qz), R12 = 2.f*(qy*qz - qx*qw);
    float R20 = 2.f*(qx*qz - qy*qw), R21 = 2.f*(qy*qz + qx*qw), R22 = 1.f - 2.f*(qx*qx + qy*qy);

    float x = pos[3*i + 0];
    float y = pos[3*i + 1];
    float z = pos[3*i + 2];

    float cx = R00*x + R01*y + R02*z + tv[0];
    float cy = R10*x + R11*y + R12*z + tv[1];
    float cz = R20*x + R21*y + R22*z + tv[2];

    float px = cx / cz * FX_C + CX_C;
    float py = cy / cz * FY_C + CY_C;

    float s   = scl[i];
    float a2  = (-0.5f / (s * s)) * LOG2E_F;

    float4 r; r.x = px; r.y = py; r.z = a2; r.w = opac[i];
    return r;
}

// ---------------------------------------------------------------------------
// Fused hot kernel, color-folded-V version.
// Block = 128x * 16y px, 256 threads, thread tile 2x*4y. grid = (8, S).
// Colors are folded into the y-factor at staging time:
//   V4[y][g] = { v*cr, v*cg, v*cb, v },  v = exp2(a2*dy^2)
// so the inner loop is 4 fma per pixel-gaussian pair (was mul+3fma+add = 5):
//   accC[y] += u * V4[y][g].C  for C in {r,g,b,den}.
// den still accumulates u*v exactly as before; num regroups u*(v*c) vs
// (u*v)*c — per-term delta ~2^-24 relative, invisible at the 2e-3 scale.
// Inner DS per j: 1 ds_read_b64 (u, 2-way alias, free) + 4 pure-broadcast
// b128 (V4 at wave-uniform addresses). No per-j color loads at all.
// LDS 49.8 KB -> 3 blocks/CU (12 waves); R2/R3 showed occupancy is not the
// lever here, VALU issue count is.
// ---------------------------------------------------------------------------
__global__ __launch_bounds__(256, 3) void gemm_fused(
    const float* __restrict__ pos, const float* __restrict__ col,
    const float* __restrict__ opac, const float* __restrict__ scl,
    const float* __restrict__ qv, const float* __restrict__ tv,
    float4* __restrict__ part, int segLen)
{
    __shared__ __align__(16) float  U_lds[CHUNK * 128];   // 32 KB [g][x]
    __shared__ __align__(16) float4 V4_lds[16 * CHUNK];   // 16 KB [y][g]
    __shared__ __align__(16) float  C_lds[3 * CHUNK];     // 768 B [ch][g]
    __shared__ __align__(16) float4 P_lds[CHUNK];         // 1 KB

    int tid = threadIdx.x;
    int xt  = tid & 63;                   // x-pair index within the 128-px row
    int wy  = (tid >> 6) * 4;             // thread's y offset (0,4,8,12)
    int yb  = blockIdx.x * 16;            // block's y base
    int g0  = blockIdx.y * segLen;

    v2f aR[4], aG[4], aB[4], aD[4];
    #pragma unroll
    for (int yi = 0; yi < 4; ++yi) { aR[yi] = 0.f; aG[yi] = 0.f; aB[yi] = 0.f; aD[yi] = 0.f; }

    for (int c0 = 0; c0 < segLen; c0 += CHUNK) {
        int cc = (segLen - c0 < CHUNK) ? (segLen - c0) : CHUNK;

        __syncthreads();                           // LDS reuse guard
        if (tid < CHUNK) {
            float4 p;
            if (tid < cc) p = proj_of(pos, opac, scl, qv, tv, g0 + c0 + tid);
            else { p.x = 0.f; p.y = 0.f; p.z = 0.f; p.w = 0.f; }  // pad -> u=0
            P_lds[tid] = p;
        } else {
            // threads 64..255 stage colors: ch = e>>6, g = e&63
            int e  = tid - 64;                     // 0..191 = 3*CHUNK
            int ch = e >> 6;
            int g  = e & 63;
            C_lds[ch * CHUNK + g] = (g < cc) ? col[3 * (g0 + c0 + g) + ch] : 0.f;
        }
        __syncthreads();

        // Stage U: e = g*128 + x, lanes consecutive -> conflict-free writes;
        // P_lds[e>>7] is wave-uniform -> broadcast read. 32 iterations.
        for (int e = tid; e < CHUNK * 128; e += 256) {
            float4 p = P_lds[e >> 7];
            float dx = (float)(e & 127) - p.x;
            U_lds[e] = p.w * __builtin_amdgcn_exp2f(p.z * dx * dx);
        }
        // Stage V4: e = g + 64*y (g lane-fast). 4 iterations, b128 writes.
        for (int e = tid; e < 16 * CHUNK; e += 256) {
            int g = e & 63, y = e >> 6;
            float4 p = P_lds[g];
            float dy = (float)(yb + y) - p.y;
            float v  = __builtin_amdgcn_exp2f(p.z * dy * dy);
            float4 q;
            q.x = v * C_lds[0 * CHUNK + g];
            q.y = v * C_lds[1 * CHUNK + g];
            q.z = v * C_lds[2 * CHUNK + g];
            q.w = v;                                // pad g: {0,0,0,1}, u=0 kills it
            V4_lds[e] = q;
        }
        __syncthreads();

        #pragma unroll 8
        for (int j = 0; j < cc; ++j) {
            v2f u = *(const v2f*)(U_lds + j * 128 + 2 * xt);     // ds_read_b64
            #pragma unroll
            for (int yi = 0; yi < 4; ++yi) {
                float4 q = V4_lds[(wy + yi) * CHUNK + j];        // broadcast b128
                aR[yi] += u * q.x;
                aG[yi] += u * q.y;
                aB[yi] += u * q.z;
                aD[yi] += u * q.w;
            }
        }
    }

    size_t segBase = (size_t)blockIdx.y * HW_IMG + 2 * xt;
    #pragma unroll
    for (int yi = 0; yi < 4; ++yi) {
        size_t b = segBase + (size_t)(yb + wy + yi) * 128;
        float4 o0, o1;
        o0.x = aR[yi].x; o0.y = aG[yi].x; o0.z = aB[yi].x; o0.w = aD[yi].x;
        o1.x = aR[yi].y; o1.y = aG[yi].y; o1.z = aB[yi].y; o1.w = aD[yi].y;
        part[b] = o0; part[b + 1] = o1;
    }
}

// ---------------------------------------------------------------------------
// Fallback hot kernel (tiny-workspace path only): direct 2-D evaluation.
// ---------------------------------------------------------------------------
__global__ __launch_bounds__(256) void render_fb(
    const float* __restrict__ pos, const float* __restrict__ col,
    const float* __restrict__ opac, const float* __restrict__ scl,
    const float* __restrict__ qv, const float* __restrict__ tv,
    float4* __restrict__ part, int segLen)
{
    int p = blockIdx.x * 256 + threadIdx.x;
    float X = (float)(p & (W_IMG - 1));
    float Y = (float)(p >> 7);

    int g0 = blockIdx.y * segLen;
    float nr = 0.f, ng = 0.f, nb = 0.f, den = 0.f;
    for (int j = 0; j < segLen; ++j) {
        int g = g0 + j;
        float4 pg = proj_of(pos, opac, scl, qv, tv, g);
        float dx = X - pg.x;
        float dy = Y - pg.y;
        float d2 = fmaf(dx, dx, dy * dy);
        float e  = pg.w * __builtin_amdgcn_exp2f(pg.z * d2);
        nr  = fmaf(e, col[3*g+0], nr);
        ng  = fmaf(e, col[3*g+1], ng);
        nb  = fmaf(e, col[3*g+2], nb);
        den += e;
    }
    float4 o; o.x = nr; o.y = ng; o.z = nb; o.w = den;
    part[(size_t)blockIdx.y * HW_IMG + p] = o;
}

// ---------------------------------------------------------------------------
// Finalize v2: 4 threads per pixel (grid = HW/64 blocks of 256), LDS
// tree-reduce of the 4 partials, then EPS, divide, tiled/transposed store.
// 32 MB of partials now read by 256 blocks (full-GPU BW) instead of 64.
// ---------------------------------------------------------------------------
__global__ __launch_bounds__(256) void finalize_kernel(
    const float4* __restrict__ part, float* __restrict__ out,
    const int* __restrict__ chunk_gauss_p, const int* __restrict__ tile_hw_p,
    int N, int nseg)
{
    __shared__ float4 red[4][64];

    int tid   = threadIdx.x;
    int pxl   = tid & 63;                  // pixel within block
    int lane4 = tid >> 6;                  // which quarter of the segments
    int p     = blockIdx.x * 64 + pxl;

    float nr = 0.f, ng = 0.f, nb = 0.f, den = 0.f;
    for (int s = lane4; s < nseg; s += 4) {
        float4 v = part[(size_t)s * HW_IMG + p];
        nr += v.x; ng += v.y; nb += v.z; den += v.w;
    }
    float4 a; a.x = nr; a.y = ng; a.z = nb; a.w = den;
    red[lane4][pxl] = a;
    __syncthreads();

    if (tid < 64) {
        float4 a0 = red[0][tid], a1 = red[1][tid], a2 = red[2][tid], a3 = red[3][tid];
        float snr = (a0.x + a1.x) + (a2.x + a3.x);
        float sng = (a0.y + a1.y) + (a2.y + a3.y);
        float snb = (a0.z + a1.z) + (a2.z + a3.z);
        float sd  = (a0.w + a1.w) + (a2.w + a3.w);

        int cg = chunk_gauss_p[0];
        int n_chunks = (cg > 0) ? (N / cg) : 0;
        sd += (float)n_chunks * 1e-8f;     // EPS added once per scan chunk

        int th   = tile_hw_p[0];
        int step = th * th;
        if (step <= 0 || step > HW_IMG) { th = 64; step = th * th; }
        int pp = blockIdx.x * 64 + tid;
        int t  = pp / step;
        int s2 = pp - t * step;
        size_t base = (size_t)t * 3 * step + s2;

        out[base]            = snr / sd;
        out[base + step]     = sng / sd;
        out[base + 2 * step] = snb / sd;
    }
}

extern "C" void kernel_launch(void* const* d_in, const int* in_sizes, int n_in,
                              void* d_out, int out_size, void* d_ws, size_t ws_size,
                              hipStream_t stream)
{
    const float* pos  = (const float*)d_in[0];
    const float* col  = (const float*)d_in[1];
    const float* opac = (const float*)d_in[2];
    const float* scl  = (const float*)d_in[3];
    const float* qv   = (const float*)d_in[4];
    const float* tv   = (const float*)d_in[5];
    const int* tile_hw_p     = (const int*)d_in[6];
    const int* chunk_gauss_p = (const int*)d_in[7];

    int N = in_sizes[2];                 // one opacity per gaussian

    // Workspace: only part[S * HW] float4 (factors live in LDS).
    int S = 0;
    for (int cand = 128; cand >= 8; cand >>= 1) {
        if (N % cand == 0 &&
            (size_t)cand * HW_IMG * 16 <= ws_size) { S = cand; break; }
    }

    float4* part = (float4*)d_ws;

    if (S > 0) {
        dim3 grid(H_IMG / 16, S);
        gemm_fused<<<grid, 256, 0, stream>>>(
            pos, col, opac, scl, qv, tv, part, N / S);

        finalize_kernel<<<HW_IMG / 64, 256, 0, stream>>>(
            part, (float*)d_out, chunk_gauss_p, tile_hw_p, N, S);
    } else {
        int nseg = 16;
        while (nseg > 1 &&
               ((size_t)nseg * HW_IMG * 16 > ws_size || (N % nseg) != 0))
            nseg >>= 1;

        dim3 grid(HW_IMG / 256, nseg);
        render_fb<<<grid, 256, 0, stream>>>(pos, col, opac, scl, qv, tv, part, N / nseg);

        finalize_kernel<<<HW_IMG / 64, 256, 0, stream>>>(
            part, (float*)d_out, chunk_gauss_p, tile_hw_p, N, nseg);
    }
}

// Round 6
// 94.794 us; speedup vs baseline: 1.4275x; 1.4275x over previous
//
#include <hip/hip_runtime.h>

typedef _Float16 f16x8 __attribute__((ext_vector_type(8)));
typedef float    f32x4 __attribute__((ext_vector_type(4)));

#define W_IMG   128
#define H_IMG   128
#define HW_IMG  16384
#define FX_C    128.0f
#define FY_C    128.0f
#define CX_C    64.0f
#define CY_C    64.0f
#define LOG2E_F 1.4426950408889634f
#define SUPER   128          // gaussians staged per LDS refill
#define KCH     32           // gaussians per MFMA K-step

// ---------------------------------------------------------------------------
// Inline per-gaussian projection: {px, py, a2, op}, a2 = -0.5/var*log2(e).
// ---------------------------------------------------------------------------
__device__ __forceinline__ float4 proj_of(
    const float* __restrict__ pos, const float* __restrict__ opac,
    const float* __restrict__ scl, const float* __restrict__ qv,
    const float* __restrict__ tv, int i)
{
    float qw = qv[0], qx = qv[1], qy = qv[2], qz = qv[3];
    float qn = sqrtf(qw*qw + qx*qx + qy*qy + qz*qz);
    qw /= qn; qx /= qn; qy /= qn; qz /= qn;

    float R00 = 1.f - 2.f*(qy*qy + qz*qz), R01 = 2.f*(qx*qy - qz*qw), R02 = 2.f*(qx*qz + qy*qw);
    float R10 = 2.f*(qx*qy + qz*qw), R11 = 1.f - 2.f*(qx*qx + qz*qz), R12 = 2.f*(qy*qz - qx*qw);
    float R20 = 2.f*(qx*qz - qy*qw), R21 = 2.f*(qy*qz + qx*qw), R22 = 1.f - 2.f*(qx*qx + qy*qy);

    float x = pos[3*i + 0];
    float y = pos[3*i + 1];
    float z = pos[3*i + 2];

    float cx = R00*x + R01*y + R02*z + tv[0];
    float cy = R10*x + R11*y + R12*z + tv[1];
    float cz = R20*x + R21*y + R22*z + tv[2];

    float px = cx / cz * FX_C + CX_C;
    float py = cy / cz * FY_C + CY_C;

    float s   = scl[i];
    float a2  = (-0.5f / (s * s)) * LOG2E_F;

    float4 r; r.x = px; r.y = py; r.z = a2; r.w = opac[i];
    return r;
}

// ---------------------------------------------------------------------------
// MFMA hot kernel. Separable factorization as a dense f16 matmul per channel:
//   D_ch[y,x] = sum_g (v[y,g]*c_ch[g]) * u[x,g]
//   A = vc (M=16 y, K=32 g), B = u (K=32 g, N=16 x), D = 16y x 16x, fp32 acc.
// Block = 256 thr (4 waves), each wave owns a 32y*32x quadrant of a 64*64 px
// tile (2 yt * 2 xt * 4 ch = 16 MFMA frags, fp32). grid = (4 img-tiles, S).
// Fragments are generated IN REGISTERS: lane l computes its 8 A/B elements
// (k = (l>>4)*8+i) from the per-gaussian param table staged in 4 KB LDS.
// A and B use the same (lane,elem)->k map, so the K-sum is invariant to the
// exact k-packing; D mapping (col=lane&15, row=(lane>>4)*4+reg) is the
// HW-verified gfx950 layout.
// No U/V LDS tiles, no per-j broadcast storm, 2 barriers per 128 gaussians.
// ---------------------------------------------------------------------------
__global__ __launch_bounds__(256, 2) void gemm_mfma(
    const float* __restrict__ pos, const float* __restrict__ col,
    const float* __restrict__ opac, const float* __restrict__ scl,
    const float* __restrict__ qv, const float* __restrict__ tv,
    float4* __restrict__ part, int segLen)
{
    __shared__ __align__(16) float4 Pa[SUPER];   // {px, py, a2, op}
    __shared__ __align__(16) float4 Pb[SUPER];   // {cr, cg, cb, -}

    int tid  = threadIdx.x;
    int lane = tid & 63;
    int wid  = tid >> 6;
    int li   = lane & 15;                 // M/N index within fragment
    int kb   = lane >> 4;                 // k-block (0..3)

    int xb = (blockIdx.x & 1) * 64 + (wid & 1) * 32;   // wave x base
    int yb = (blockIdx.x >> 1) * 64 + (wid >> 1) * 32; // wave y base
    int g0 = blockIdx.y * segLen;

    f32x4 aR[2][2], aG[2][2], aB[2][2], aD[2][2];      // [yt][xt]
    #pragma unroll
    for (int yt = 0; yt < 2; ++yt)
        #pragma unroll
        for (int xt = 0; xt < 2; ++xt) {
            aR[yt][xt] = (f32x4)0.f; aG[yt][xt] = (f32x4)0.f;
            aB[yt][xt] = (f32x4)0.f; aD[yt][xt] = (f32x4)0.f;
        }

    for (int s0 = 0; s0 < segLen; s0 += SUPER) {
        int sc = (segLen - s0 < SUPER) ? (segLen - s0) : SUPER;

        __syncthreads();                           // LDS reuse guard
        if (tid < sc) {
            Pa[tid] = proj_of(pos, opac, scl, qv, tv, g0 + s0 + tid);
        } else if (tid >= 128) {
            for (int k = tid - 128; k < 3 * sc; k += 128) {
                int g  = k / 3;                    // magic-mul
                int ch = k - 3 * g;
                reinterpret_cast<float*>(Pb)[g * 4 + ch] =
                    col[3 * (g0 + s0 + g) + ch];
            }
        }
        __syncthreads();

        for (int c0 = 0; c0 < sc; c0 += KCH) {
            // Pull this lane's 8 gaussians' params (broadcast b128 reads).
            float px_[8], py_[8], a2_[8], op_[8], cr_[8], cg_[8], cb_[8];
            #pragma unroll
            for (int i = 0; i < 8; ++i) {
                int gg = c0 + kb * 8 + i;
                float4 a = Pa[gg];
                float4 b = Pb[gg];
                px_[i] = a.x; py_[i] = a.y; a2_[i] = a.z; op_[i] = a.w;
                cr_[i] = b.x; cg_[i] = b.y; cb_[i] = b.z;
            }

            // B fragments: u[x,g] = op*exp2(a2*dx^2), x = xb + xt*16 + li.
            f16x8 Bu[2];
            #pragma unroll
            for (int xt = 0; xt < 2; ++xt) {
                float X = (float)(xb + xt * 16 + li);
                #pragma unroll
                for (int i = 0; i < 8; ++i) {
                    float dx = X - px_[i];
                    float u  = op_[i] * __builtin_amdgcn_exp2f(a2_[i] * dx * dx);
                    Bu[xt][i] = (_Float16)u;
                }
            }

            // A fragments per yt (v and v*c), then 8 MFMAs for this yt.
            #pragma unroll
            for (int yt = 0; yt < 2; ++yt) {
                float Y = (float)(yb + yt * 16 + li);
                f16x8 Ar, Ag, Ab2, Ad;
                #pragma unroll
                for (int i = 0; i < 8; ++i) {
                    float dy = Y - py_[i];
                    float v  = __builtin_amdgcn_exp2f(a2_[i] * dy * dy);
                    Ad[i]  = (_Float16)v;
                    Ar[i]  = (_Float16)(v * cr_[i]);
                    Ag[i]  = (_Float16)(v * cg_[i]);
                    Ab2[i] = (_Float16)(v * cb_[i]);
                }
                #pragma unroll
                for (int xt = 0; xt < 2; ++xt) {
                    aR[yt][xt] = __builtin_amdgcn_mfma_f32_16x16x32_f16(
                        Ar,  Bu[xt], aR[yt][xt], 0, 0, 0);
                    aG[yt][xt] = __builtin_amdgcn_mfma_f32_16x16x32_f16(
                        Ag,  Bu[xt], aG[yt][xt], 0, 0, 0);
                    aB[yt][xt] = __builtin_amdgcn_mfma_f32_16x16x32_f16(
                        Ab2, Bu[xt], aB[yt][xt], 0, 0, 0);
                    aD[yt][xt] = __builtin_amdgcn_mfma_f32_16x16x32_f16(
                        Ad,  Bu[xt], aD[yt][xt], 0, 0, 0);
                }
            }
        }
    }

    // Epilogue: D layout col = lane&15 (x), row = (lane>>4)*4 + reg (y).
    // Lanes 0-15 write 16 consecutive float4 -> 256B contiguous per store.
    size_t segBase = (size_t)blockIdx.y * HW_IMG;
    #pragma unroll
    for (int yt = 0; yt < 2; ++yt)
        #pragma unroll
        for (int xt = 0; xt < 2; ++xt)
            #pragma unroll
            for (int i = 0; i < 4; ++i) {
                int y = yb + yt * 16 + kb * 4 + i;
                int x = xb + xt * 16 + li;
                float4 o;
                o.x = aR[yt][xt][i]; o.y = aG[yt][xt][i];
                o.z = aB[yt][xt][i]; o.w = aD[yt][xt][i];
                part[segBase + (size_t)y * 128 + x] = o;
            }
}

// ---------------------------------------------------------------------------
// Fallback hot kernel (tiny-workspace path only): direct 2-D evaluation.
// ---------------------------------------------------------------------------
__global__ __launch_bounds__(256) void render_fb(
    const float* __restrict__ pos, const float* __restrict__ col,
    const float* __restrict__ opac, const float* __restrict__ scl,
    const float* __restrict__ qv, const float* __restrict__ tv,
    float4* __restrict__ part, int segLen)
{
    int p = blockIdx.x * 256 + threadIdx.x;
    float X = (float)(p & (W_IMG - 1));
    float Y = (float)(p >> 7);

    int g0 = blockIdx.y * segLen;
    float nr = 0.f, ng = 0.f, nb = 0.f, den = 0.f;
    for (int j = 0; j < segLen; ++j) {
        int g = g0 + j;
        float4 pg = proj_of(pos, opac, scl, qv, tv, g);
        float dx = X - pg.x;
        float dy = Y - pg.y;
        float d2 = fmaf(dx, dx, dy * dy);
        float e  = pg.w * __builtin_amdgcn_exp2f(pg.z * d2);
        nr  = fmaf(e, col[3*g+0], nr);
        ng  = fmaf(e, col[3*g+1], ng);
        nb  = fmaf(e, col[3*g+2], nb);
        den += e;
    }
    float4 o; o.x = nr; o.y = ng; o.z = nb; o.w = den;
    part[(size_t)blockIdx.y * HW_IMG + p] = o;
}

// ---------------------------------------------------------------------------
// Finalize: sequential segment reduce (matches reference scan order),
// add n_chunks*EPS, divide, tiled/transposed fp32 output.
// ---------------------------------------------------------------------------
__global__ __launch_bounds__(256) void finalize_kernel(
    const float4* __restrict__ part, float* __restrict__ out,
    const int* __restrict__ chunk_gauss_p, const int* __restrict__ tile_hw_p,
    int N, int nseg)
{
    int p = blockIdx.x * 256 + threadIdx.x;

    float nr = 0.f, ng = 0.f, nb = 0.f, den = 0.f;
    #pragma unroll 8
    for (int s = 0; s < nseg; ++s) {
        float4 v = part[(size_t)s * HW_IMG + p];
        nr += v.x; ng += v.y; nb += v.z; den += v.w;
    }

    int cg = chunk_gauss_p[0];
    int n_chunks = (cg > 0) ? (N / cg) : 0;
    den += (float)n_chunks * 1e-8f;   // EPS added once per scan chunk

    int th   = tile_hw_p[0];
    int step = th * th;
    if (step <= 0 || step > HW_IMG) { th = 64; step = th * th; }
    int t  = p / step;
    int s2 = p - t * step;
    size_t base = (size_t)t * 3 * step + s2;

    out[base]            = nr / den;
    out[base + step]     = ng / den;
    out[base + 2 * step] = nb / den;
}

extern "C" void kernel_launch(void* const* d_in, const int* in_sizes, int n_in,
                              void* d_out, int out_size, void* d_ws, size_t ws_size,
                              hipStream_t stream)
{
    const float* pos  = (const float*)d_in[0];
    const float* col  = (const float*)d_in[1];
    const float* opac = (const float*)d_in[2];
    const float* scl  = (const float*)d_in[3];
    const float* qv   = (const float*)d_in[4];
    const float* tv   = (const float*)d_in[5];
    const int* tile_hw_p     = (const int*)d_in[6];
    const int* chunk_gauss_p = (const int*)d_in[7];

    int N = in_sizes[2];                 // one opacity per gaussian

    // Workspace: part[S * HW] float4. MFMA path needs segLen % 32 == 0.
    int S = 0;
    for (int cand = 128; cand >= 8; cand >>= 1) {
        if (N % cand == 0 && ((N / cand) % KCH) == 0 &&
            (size_t)cand * HW_IMG * 16 <= ws_size) { S = cand; break; }
    }

    float4* part = (float4*)d_ws;

    if (S > 0) {
        dim3 grid(4, S);                 // 4 img-tiles of 64x64 px
        gemm_mfma<<<grid, 256, 0, stream>>>(
            pos, col, opac, scl, qv, tv, part, N / S);

        finalize_kernel<<<HW_IMG / 256, 256, 0, stream>>>(
            part, (float*)d_out, chunk_gauss_p, tile_hw_p, N, S);
    } else {
        int nseg = 16;
        while (nseg > 1 &&
               ((size_t)nseg * HW_IMG * 16 > ws_size || (N % nseg) != 0))
            nseg >>= 1;

        dim3 grid(HW_IMG / 256, nseg);
        render_fb<<<grid, 256, 0, stream>>>(pos, col, opac, scl, qv, tv, part, N / nseg);

        finalize_kernel<<<HW_IMG / 256, 256, 0, stream>>>(
            part, (float*)d_out, chunk_gauss_p, tile_hw_p, N, nseg);
    }
}

// Round 7
// 89.688 us; speedup vs baseline: 1.5087x; 1.0569x over previous
//
#include <hip/hip_runtime.h>

typedef _Float16 f16x8 __attribute__((ext_vector_type(8)));
typedef float    f32x4 __attribute__((ext_vector_type(4)));

#define W_IMG   128
#define H_IMG   128
#define HW_IMG  16384
#define FX_C    128.0f
#define FY_C    128.0f
#define CX_C    64.0f
#define CY_C    64.0f
#define LOG2E_F 1.4426950408889634f
#define SUPER   128          // gaussians staged per LDS refill
#define KCH     32           // gaussians per MFMA K-step

// ---------------------------------------------------------------------------
// Inline per-gaussian projection: {px, py, a2, op}, a2 = -0.5/var*log2(e).
// ---------------------------------------------------------------------------
__device__ __forceinline__ float4 proj_of(
    const float* __restrict__ pos, const float* __restrict__ opac,
    const float* __restrict__ scl, const float* __restrict__ qv,
    const float* __restrict__ tv, int i)
{
    float qw = qv[0], qx = qv[1], qy = qv[2], qz = qv[3];
    float qn = sqrtf(qw*qw + qx*qx + qy*qy + qz*qz);
    qw /= qn; qx /= qn; qy /= qn; qz /= qn;

    float R00 = 1.f - 2.f*(qy*qy + qz*qz), R01 = 2.f*(qx*qy - qz*qw), R02 = 2.f*(qx*qz + qy*qw);
    float R10 = 2.f*(qx*qy + qz*qw), R11 = 1.f - 2.f*(qx*qx + qz*qz), R12 = 2.f*(qy*qz - qx*qw);
    float R20 = 2.f*(qx*qz - qy*qw), R21 = 2.f*(qy*qz + qx*qw), R22 = 1.f - 2.f*(qx*qx + qy*qy);

    float x = pos[3*i + 0];
    float y = pos[3*i + 1];
    float z = pos[3*i + 2];

    float cx = R00*x + R01*y + R02*z + tv[0];
    float cy = R10*x + R11*y + R12*z + tv[1];
    float cz = R20*x + R21*y + R22*z + tv[2];

    float px = cx / cz * FX_C + CX_C;
    float py = cy / cz * FY_C + CY_C;

    float s   = scl[i];
    float a2  = (-0.5f / (s * s)) * LOG2E_F;

    float4 r; r.x = px; r.y = py; r.z = a2; r.w = opac[i];
    return r;
}

// ---------------------------------------------------------------------------
// MFMA hot kernel. Separable factorization as a dense f16 matmul per channel:
//   D_ch[y,x] = sum_g (v[y,g]*c_ch[g]) * u[x,g]
//   A = vc (M=16 y, K=32 g), B = u (K=32 g, N=16 x), D = 16y x 16x, fp32 acc.
// Block = 256 thr (4 waves); block tile = 64x*32y px; wave quadrant =
// 32x*16y (2 xt * 1 yt * 4 ch = 8 MFMA frags). grid = (8 img-tiles, S=64)
// = 512 blocks = 2/CU. Fragments generated IN REGISTERS from a 4 KB LDS
// param table; A and B share the same (lane,elem)->k map so the K-sum is
// packing-invariant; D mapping (col=lane&15, row=(lane>>4)*4+reg) is the
// HW-verified gfx950 layout. part shrinks to 16 MB (S=64).
// ---------------------------------------------------------------------------
__global__ __launch_bounds__(256, 2) void gemm_mfma(
    const float* __restrict__ pos, const float* __restrict__ col,
    const float* __restrict__ opac, const float* __restrict__ scl,
    const float* __restrict__ qv, const float* __restrict__ tv,
    float4* __restrict__ part, int segLen)
{
    __shared__ __align__(16) float4 Pa[SUPER];   // {px, py, a2, op}
    __shared__ __align__(16) float4 Pb[SUPER];   // {cr, cg, cb, -}

    int tid  = threadIdx.x;
    int lane = tid & 63;
    int wid  = tid >> 6;
    int li   = lane & 15;                 // M/N index within fragment
    int kb   = lane >> 4;                 // k-block (0..3)

    // 8 image tiles of 64x32: x in {0,64}, y in {0,32,64,96}.
    int xb = (blockIdx.x & 1) * 64 + (wid & 1) * 32;   // wave x base
    int yb = (blockIdx.x >> 1) * 32 + (wid >> 1) * 16; // wave y base
    int g0 = blockIdx.y * segLen;

    f32x4 aR[2], aG[2], aB[2], aD[2];     // [xt]
    #pragma unroll
    for (int xt = 0; xt < 2; ++xt) {
        aR[xt] = (f32x4)0.f; aG[xt] = (f32x4)0.f;
        aB[xt] = (f32x4)0.f; aD[xt] = (f32x4)0.f;
    }

    for (int s0 = 0; s0 < segLen; s0 += SUPER) {
        int sc = (segLen - s0 < SUPER) ? (segLen - s0) : SUPER;

        __syncthreads();                           // LDS reuse guard
        if (tid < sc) {
            Pa[tid] = proj_of(pos, opac, scl, qv, tv, g0 + s0 + tid);
        } else if (tid >= 128) {
            for (int k = tid - 128; k < 3 * sc; k += 128) {
                int g  = k / 3;                    // magic-mul
                int ch = k - 3 * g;
                reinterpret_cast<float*>(Pb)[g * 4 + ch] =
                    col[3 * (g0 + s0 + g) + ch];
            }
        }
        __syncthreads();

        for (int c0 = 0; c0 < sc; c0 += KCH) {
            // Pull this lane's 8 gaussians' params (broadcast b128 reads).
            float px_[8], py_[8], a2_[8], op_[8], cr_[8], cg_[8], cb_[8];
            #pragma unroll
            for (int i = 0; i < 8; ++i) {
                int gg = c0 + kb * 8 + i;
                float4 a = Pa[gg];
                float4 b = Pb[gg];
                px_[i] = a.x; py_[i] = a.y; a2_[i] = a.z; op_[i] = a.w;
                cr_[i] = b.x; cg_[i] = b.y; cb_[i] = b.z;
            }

            // B fragments: u[x,g] = op*exp2(a2*dx^2), x = xb + xt*16 + li.
            f16x8 Bu[2];
            #pragma unroll
            for (int xt = 0; xt < 2; ++xt) {
                float X = (float)(xb + xt * 16 + li);
                #pragma unroll
                for (int i = 0; i < 8; ++i) {
                    float dx = X - px_[i];
                    float u  = op_[i] * __builtin_amdgcn_exp2f(a2_[i] * dx * dx);
                    Bu[xt][i] = (_Float16)u;
                }
            }

            // A fragments (v and v*c) for this wave's single y-row of frags.
            {
                float Y = (float)(yb + li);
                f16x8 Ar, Ag, Ab2, Ad;
                #pragma unroll
                for (int i = 0; i < 8; ++i) {
                    float dy = Y - py_[i];
                    float v  = __builtin_amdgcn_exp2f(a2_[i] * dy * dy);
                    Ad[i]  = (_Float16)v;
                    Ar[i]  = (_Float16)(v * cr_[i]);
                    Ag[i]  = (_Float16)(v * cg_[i]);
                    Ab2[i] = (_Float16)(v * cb_[i]);
                }
                #pragma unroll
                for (int xt = 0; xt < 2; ++xt) {
                    aR[xt] = __builtin_amdgcn_mfma_f32_16x16x32_f16(
                        Ar,  Bu[xt], aR[xt], 0, 0, 0);
                    aG[xt] = __builtin_amdgcn_mfma_f32_16x16x32_f16(
                        Ag,  Bu[xt], aG[xt], 0, 0, 0);
                    aB[xt] = __builtin_amdgcn_mfma_f32_16x16x32_f16(
                        Ab2, Bu[xt], aB[xt], 0, 0, 0);
                    aD[xt] = __builtin_amdgcn_mfma_f32_16x16x32_f16(
                        Ad,  Bu[xt], aD[xt], 0, 0, 0);
                }
            }
        }
    }

    // Epilogue: D layout col = lane&15 (x), row = (lane>>4)*4 + reg (y).
    size_t segBase = (size_t)blockIdx.y * HW_IMG;
    #pragma unroll
    for (int xt = 0; xt < 2; ++xt)
        #pragma unroll
        for (int i = 0; i < 4; ++i) {
            int y = yb + kb * 4 + i;
            int x = xb + xt * 16 + li;
            float4 o;
            o.x = aR[xt][i]; o.y = aG[xt][i];
            o.z = aB[xt][i]; o.w = aD[xt][i];
            part[segBase + (size_t)y * 128 + x] = o;
        }
}

// ---------------------------------------------------------------------------
// Fallback hot kernel (tiny-workspace path only): direct 2-D evaluation.
// ---------------------------------------------------------------------------
__global__ __launch_bounds__(256) void render_fb(
    const float* __restrict__ pos, const float* __restrict__ col,
    const float* __restrict__ opac, const float* __restrict__ scl,
    const float* __restrict__ qv, const float* __restrict__ tv,
    float4* __restrict__ part, int segLen)
{
    int p = blockIdx.x * 256 + threadIdx.x;
    float X = (float)(p & (W_IMG - 1));
    float Y = (float)(p >> 7);

    int g0 = blockIdx.y * segLen;
    float nr = 0.f, ng = 0.f, nb = 0.f, den = 0.f;
    for (int j = 0; j < segLen; ++j) {
        int g = g0 + j;
        float4 pg = proj_of(pos, opac, scl, qv, tv, g);
        float dx = X - pg.x;
        float dy = Y - pg.y;
        float d2 = fmaf(dx, dx, dy * dy);
        float e  = pg.w * __builtin_amdgcn_exp2f(pg.z * d2);
        nr  = fmaf(e, col[3*g+0], nr);
        ng  = fmaf(e, col[3*g+1], ng);
        nb  = fmaf(e, col[3*g+2], nb);
        den += e;
    }
    float4 o; o.x = nr; o.y = ng; o.z = nb; o.w = den;
    part[(size_t)blockIdx.y * HW_IMG + p] = o;
}

// ---------------------------------------------------------------------------
// Finalize v3: 4 threads per pixel (grid = HW/64 = 256 blocks of 256),
// strided segment partials + LDS tree-reduce, then EPS, divide,
// tiled/transposed fp32 output. Full-GPU BW on the part read.
// ---------------------------------------------------------------------------
__global__ __launch_bounds__(256) void finalize_kernel(
    const float4* __restrict__ part, float* __restrict__ out,
    const int* __restrict__ chunk_gauss_p, const int* __restrict__ tile_hw_p,
    int N, int nseg)
{
    __shared__ float4 red[4][64];

    int tid   = threadIdx.x;
    int pxl   = tid & 63;                  // pixel within block
    int lane4 = tid >> 6;                  // which quarter of the segments
    int p     = blockIdx.x * 64 + pxl;

    float nr = 0.f, ng = 0.f, nb = 0.f, den = 0.f;
    for (int s = lane4; s < nseg; s += 4) {
        float4 v = part[(size_t)s * HW_IMG + p];
        nr += v.x; ng += v.y; nb += v.z; den += v.w;
    }
    float4 a; a.x = nr; a.y = ng; a.z = nb; a.w = den;
    red[lane4][pxl] = a;
    __syncthreads();

    if (tid < 64) {
        float4 a0 = red[0][tid], a1 = red[1][tid], a2 = red[2][tid], a3 = red[3][tid];
        float snr = (a0.x + a1.x) + (a2.x + a3.x);
        float sng = (a0.y + a1.y) + (a2.y + a3.y);
        float snb = (a0.z + a1.z) + (a2.z + a3.z);
        float sd  = (a0.w + a1.w) + (a2.w + a3.w);

        int cg = chunk_gauss_p[0];
        int n_chunks = (cg > 0) ? (N / cg) : 0;
        sd += (float)n_chunks * 1e-8f;     // EPS added once per scan chunk

        int th   = tile_hw_p[0];
        int step = th * th;
        if (step <= 0 || step > HW_IMG) { th = 64; step = th * th; }
        int pp = blockIdx.x * 64 + tid;
        int t  = pp / step;
        int s2 = pp - t * step;
        size_t base = (size_t)t * 3 * step + s2;

        out[base]            = snr / sd;
        out[base + step]     = sng / sd;
        out[base + 2 * step] = snb / sd;
    }
}

extern "C" void kernel_launch(void* const* d_in, const int* in_sizes, int n_in,
                              void* d_out, int out_size, void* d_ws, size_t ws_size,
                              hipStream_t stream)
{
    const float* pos  = (const float*)d_in[0];
    const float* col  = (const float*)d_in[1];
    const float* opac = (const float*)d_in[2];
    const float* scl  = (const float*)d_in[3];
    const float* qv   = (const float*)d_in[4];
    const float* tv   = (const float*)d_in[5];
    const int* tile_hw_p     = (const int*)d_in[6];
    const int* chunk_gauss_p = (const int*)d_in[7];

    int N = in_sizes[2];                 // one opacity per gaussian

    // Workspace: part[S * HW] float4. MFMA path needs segLen % 32 == 0.
    int S = 0;
    for (int cand = 64; cand >= 8; cand >>= 1) {
        if (N % cand == 0 && ((N / cand) % KCH) == 0 &&
            (size_t)cand * HW_IMG * 16 <= ws_size) { S = cand; break; }
    }

    float4* part = (float4*)d_ws;

    if (S > 0) {
        dim3 grid(8, S);                 // 8 img-tiles of 64x32 px
        gemm_mfma<<<grid, 256, 0, stream>>>(
            pos, col, opac, scl, qv, tv, part, N / S);

        finalize_kernel<<<HW_IMG / 64, 256, 0, stream>>>(
            part, (float*)d_out, chunk_gauss_p, tile_hw_p, N, S);
    } else {
        int nseg = 16;
        while (nseg > 1 &&
               ((size_t)nseg * HW_IMG * 16 > ws_size || (N % nseg) != 0))
            nseg >>= 1;

        dim3 grid(HW_IMG / 256, nseg);
        render_fb<<<grid, 256, 0, stream>>>(pos, col, opac, scl, qv, tv, part, N / nseg);

        finalize_kernel<<<HW_IMG / 64, 256, 0, stream>>>(
            part, (float*)d_out, chunk_gauss_p, tile_hw_p, N, nseg);
    }
}